// Round 1
// baseline (5337.277 us; speedup 1.0000x reference)
//
#include <hip/hip_runtime.h>
#include <hip/hip_bf16.h>

// Conv2d 3x3 SAME, stride 1, NCHW fp32.
// x: (16, 64, 256, 256), w: (128, 64, 3, 3), bias: (128,)
// out: (16, 128, 256, 256)
//
// Baseline: direct conv. Block = 16x16 output pixels x 4 output channels.
// Weights for the 4 couts staged in LDS (broadcast reads -> no bank conflicts).
// Input loads coalesced along W; 3x3 + 4-cout reuse served by L1/L2.

#define H 256
#define W 256
#define CIN 64
#define COUT 128
#define NB 16

__global__ __launch_bounds__(256) void Conv2dManual_77695958385099_kernel(
    const float* __restrict__ x, const float* __restrict__ w,
    const float* __restrict__ bias, float* __restrict__ out) {
    const int tx = threadIdx.x & 15;
    const int ty = threadIdx.x >> 4;
    const int ow = blockIdx.x * 16 + tx;
    const int oh = blockIdx.y * 16 + ty;
    const int z = blockIdx.z;
    const int co = (z & 31) * 4;       // 32 groups of 4 couts
    const int n  = z >> 5;

    __shared__ float wsh[4][CIN][9];   // 9.2 KB
    for (int i = threadIdx.x; i < 4 * CIN * 9; i += 256) {
        const int cc  = i / (CIN * 9);
        const int rem = i % (CIN * 9);
        wsh[cc][rem / 9][rem % 9] = w[(size_t)(co + cc) * CIN * 9 + rem];
    }
    __syncthreads();

    float acc0 = bias[co + 0];
    float acc1 = bias[co + 1];
    float acc2 = bias[co + 2];
    float acc3 = bias[co + 3];

    const float* xn = x + (size_t)n * CIN * H * W;
    for (int ci = 0; ci < CIN; ++ci) {
        const float* xc = xn + (size_t)ci * H * W;
#pragma unroll
        for (int ky = 0; ky < 3; ++ky) {
            const int iy = oh + ky - 1;
            const bool yok = ((unsigned)iy < (unsigned)H);
#pragma unroll
            for (int kx = 0; kx < 3; ++kx) {
                const int ix = ow + kx - 1;
                const float v = (yok && (unsigned)ix < (unsigned)W)
                                    ? xc[iy * W + ix] : 0.0f;
                const int k = ky * 3 + kx;
                acc0 += v * wsh[0][ci][k];
                acc1 += v * wsh[1][ci][k];
                acc2 += v * wsh[2][ci][k];
                acc3 += v * wsh[3][ci][k];
            }
        }
    }

    const size_t hw = (size_t)H * W;
    const size_t ob = ((size_t)n * COUT + co) * hw + (size_t)oh * W + ow;
    out[ob]          = acc0;
    out[ob + hw]     = acc1;
    out[ob + 2 * hw] = acc2;
    out[ob + 3 * hw] = acc3;
}

extern "C" void kernel_launch(void* const* d_in, const int* in_sizes, int n_in,
                              void* d_out, int out_size, void* d_ws, size_t ws_size,
                              hipStream_t stream) {
    const float* x = (const float*)d_in[0];
    const float* w = (const float*)d_in[1];
    const float* b = (const float*)d_in[2];
    float* out = (float*)d_out;

    dim3 grid(W / 16, H / 16, NB * (COUT / 4));  // (16, 16, 512)
    Conv2dManual_77695958385099_kernel<<<grid, 256, 0, stream>>>(x, w, b, out);
}